// Round 4
// baseline (389.475 us; speedup 1.0000x reference)
//
#include <hip/hip_runtime.h>
#include <hip/hip_bf16.h>
#include <math.h>

#define V     8000
#define D_    300
#define B_    128
#define L_    300
#define C_    54
#define CHUNK 10            // d-chunk per block; 300 = 30 * 10
#define STR   11            // padded LDS row stride (b32 reads, <=2-way bank alias = free)
#define NELEM (L_ * CHUNK)  // 3000
#define LRUN  12            // l's per thread; 25 groups * 12 = 300
#define NGRP  25

// ---------------- Kernel 1: gather edge weights + eta ----------------
__global__ __launch_bounds__(256) void wgather_kernel(
    const float* __restrict__ edge_w,
    const float* __restrict__ node_eta,
    const int*   __restrict__ docs,
    const int*   __restrict__ edges_matrix,
    float* __restrict__ w_ws,
    float* __restrict__ eta_ws)
{
    int idx = blockIdx.x * 256 + threadIdx.x;
    if (idx >= B_ * L_ * 7) return;
    int b   = idx / (L_ * 7);
    int rem = idx - b * (L_ * 7);
    int l   = rem / 7;
    int o   = rem - l * 7;
    const int* drow = docs + b * L_;
    int d1 = drow[l];
    int nb = min(max(l + o - 3, 0), L_ - 1);
    int d2 = drow[nb];
    int eid = edges_matrix[(size_t)d1 * V + d2];
    w_ws[((size_t)b * L_ + l) * 8 + o] = edge_w[eid];
    if (o == 3) eta_ws[b * L_ + l] = node_eta[d1];
}

// ---------------- Kernel 2: propagation (sliding-window, reg w/eta) ----------------
// grid (30, 128), block 256 (250 active in compute).
// thread = (dd = tid%10, lg = tid/10): handles l in [lg*12, lg*12+12) for its dd.
__device__ __forceinline__ void prop_step(
    const float* __restrict__ src, float* __restrict__ dst,
    int l0, int dd, int lg, bool active,
    const float w[LRUN][8], const float eta[LRUN])
{
    float win[18];
    #pragma unroll
    for (int i = 0; i < 18; ++i) {
        int l = min(max(l0 - 3 + i, 0), L_ - 1);
        win[i] = src[l * STR + dd];
    }
    if (active) {
        if (lg > 0 && lg < NGRP - 1) {
            // interior: all 7 neighbors valid
            #pragma unroll
            for (int j = 0; j < LRUN; ++j) {
                float own = win[j + 3];
                float m = w[j][0] * win[j];
                m = fmaxf(m, w[j][1] * win[j + 1]);
                m = fmaxf(m, w[j][2] * win[j + 2]);
                m = fmaxf(m, w[j][3] * own);
                m = fmaxf(m, w[j][4] * win[j + 4]);
                m = fmaxf(m, w[j][5] * win[j + 5]);
                m = fmaxf(m, w[j][6] * win[j + 6]);
                float et = eta[j];
                dst[(l0 + j) * STR + dd] = et * own + (1.f - et) * m;
            }
        } else {
            #pragma unroll
            for (int j = 0; j < LRUN; ++j) {
                int l = l0 + j;
                float own = win[j + 3];
                float m = -3.402823466e38f;
                #pragma unroll
                for (int o = 0; o < 7; ++o) {
                    int nb = l - 3 + o;
                    if (nb >= 0 && nb < L_)
                        m = fmaxf(m, w[j][o] * win[j + o]);
                }
                float et = eta[j];
                dst[l * STR + dd] = et * own + (1.f - et) * m;
            }
        }
    }
}

__global__ __launch_bounds__(256) void prop_kernel(
    const float* __restrict__ node_embed,
    const float* __restrict__ eta_ws,
    const float* __restrict__ w_ws,
    const int*   __restrict__ docs,
    float* __restrict__ pooled)   // [B][D]
{
    int b   = blockIdx.y;
    int d0  = blockIdx.x * CHUNK;
    int tid = threadIdx.x;

    __shared__ float h_a[L_ * STR];      // 13200 B
    __shared__ float h_b[L_ * STR];      // 13200 B
    __shared__ float red[NGRP * CHUNK];  //  1000 B  -> ~27.4 KB total

    // cooperative h0 load (coalesced-ish: 10 consecutive dd per l)
    #pragma unroll
    for (int k = 0; k < 12; ++k) {
        int e = tid + k * 256;
        if (e < NELEM) {
            int l  = e / CHUNK;
            int dd = e - l * CHUNK;
            int row = docs[b * L_ + l];
            h_a[l * STR + dd] = node_embed[(size_t)row * D_ + d0 + dd];
        }
    }

    int dd = tid % CHUNK;
    int lg = tid / CHUNK;            // 0..25 (25 = inactive tail)
    bool active = (tid < NGRP * CHUNK);
    int lgc = min(lg, NGRP - 1);
    int l0  = lgc * LRUN;

    // w[l][0..6] and eta[l] into registers, once, used by both steps
    float w[LRUN][8];
    float eta[LRUN];
    {
        const float4* wp = (const float4*)(w_ws + ((size_t)b * L_ + l0) * 8);
        #pragma unroll
        for (int j = 0; j < LRUN; ++j) {
            float4 lo = wp[2 * j];
            float4 hi = wp[2 * j + 1];
            w[j][0] = lo.x; w[j][1] = lo.y; w[j][2] = lo.z; w[j][3] = lo.w;
            w[j][4] = hi.x; w[j][5] = hi.y; w[j][6] = hi.z; w[j][7] = 0.f;
        }
        const float4* ep = (const float4*)(eta_ws + b * L_ + l0);
        #pragma unroll
        for (int j = 0; j < 3; ++j) {
            float4 v = ep[j];
            eta[4 * j + 0] = v.x; eta[4 * j + 1] = v.y;
            eta[4 * j + 2] = v.z; eta[4 * j + 3] = v.w;
        }
    }
    __syncthreads();

    prop_step(h_a, h_b, l0, dd, lgc, active, w, eta);
    __syncthreads();
    prop_step(h_b, h_a, l0, dd, lgc, active, w, eta);
    __syncthreads();

    // pooled[b, d0+dd] = sum_l h_a[l][dd]
    int grp = tid / CHUNK;
    int dd2 = tid - grp * CHUNK;
    if (grp < NGRP) {
        float s = 0.f;
        #pragma unroll
        for (int j = 0; j < 12; ++j)
            s += h_a[(grp + j * NGRP) * STR + dd2];
        red[grp * CHUNK + dd2] = s;
    }
    __syncthreads();
    if (tid < CHUNK) {
        float s = 0.f;
        #pragma unroll
        for (int g = 0; g < NGRP; ++g) s += red[g * CHUNK + tid];
        pooled[b * D_ + d0 + tid] = s;
    }
}

// ---------------- Kernel 3: relu + batchnorm over batch axis ----------------
__global__ __launch_bounds__(128) void bn_kernel(
    const float* __restrict__ pooled,
    const float* __restrict__ gamma,
    const float* __restrict__ beta,
    float* __restrict__ xn)
{
    int d = blockIdx.x;
    int b = threadIdx.x;
    float x = fmaxf(pooled[b * D_ + d], 0.f);

    float v1 = x, v2 = x * x;
    #pragma unroll
    for (int off = 32; off > 0; off >>= 1) {
        v1 += __shfl_down(v1, off, 64);
        v2 += __shfl_down(v2, off, 64);
    }
    __shared__ float s1[2], s2[2];
    int lane = b & 63, wv = b >> 6;
    if (lane == 0) { s1[wv] = v1; s2[wv] = v2; }
    __syncthreads();
    float mean = (s1[0] + s1[1]) * (1.f / 128.f);
    float var  = (s2[0] + s2[1]) * (1.f / 128.f) - mean * mean;
    float xh = (x - mean) / sqrtf(var + 1e-5f);
    xn[b * D_ + d] = xh * gamma[d] + beta[d];
}

// ---------------- Kernel 4: matmul + bias + sigmoid ----------------
__global__ __launch_bounds__(64) void out_kernel(
    const float* __restrict__ xn,
    const float* __restrict__ Wm,
    const float* __restrict__ bias,
    float* __restrict__ out)
{
    int b = blockIdx.x;
    int c = threadIdx.x;
    if (c >= C_) return;
    float acc = bias[c];
    for (int k = 0; k < D_; ++k)
        acc = fmaf(xn[b * D_ + k], Wm[k * C_ + c], acc);
    out[b * C_ + c] = 1.f / (1.f + expf(-acc));
}

extern "C" void kernel_launch(void* const* d_in, const int* in_sizes, int n_in,
                              void* d_out, int out_size, void* d_ws, size_t ws_size,
                              hipStream_t stream) {
    const float* node_embed   = (const float*)d_in[0];
    const float* node_eta     = (const float*)d_in[1];
    const float* edge_w       = (const float*)d_in[2];
    const float* bn_gamma     = (const float*)d_in[3];
    const float* bn_beta      = (const float*)d_in[4];
    const float* Wm           = (const float*)d_in[5];
    const float* bias         = (const float*)d_in[6];
    const int*   docs         = (const int*)d_in[7];
    const int*   edges_matrix = (const int*)d_in[8];
    float* out = (float*)d_out;

    float* w_ws   = (float*)d_ws;                       // B*L*8
    float* eta_ws = w_ws + (size_t)B_ * L_ * 8;         // B*L
    float* pooled = eta_ws + (size_t)B_ * L_;           // B*D
    float* xn     = pooled + (size_t)B_ * D_;           // B*D

    {
        int total = B_ * L_ * 7;
        wgather_kernel<<<(total + 255) / 256, 256, 0, stream>>>(
            edge_w, node_eta, docs, edges_matrix, w_ws, eta_ws);
    }
    {
        dim3 grid(D_ / CHUNK, B_);  // (30, 128)
        prop_kernel<<<grid, 256, 0, stream>>>(node_embed, eta_ws, w_ws, docs, pooled);
    }
    bn_kernel<<<D_, 128, 0, stream>>>(pooled, bn_gamma, bn_beta, xn);
    out_kernel<<<B_, 64, 0, stream>>>(xn, Wm, bias, out);
}